// Round 11
// baseline (674.632 us; speedup 1.0000x reference)
//
#include <hip/hip_runtime.h>
#include <math.h>

namespace {

typedef _Float16 f16;
typedef _Float16 f16x8 __attribute__((ext_vector_type(8)));
typedef float    f32x4 __attribute__((ext_vector_type(4)));

constexpr int kBT = 1024, kD1 = 256, kD2 = 128, kDM = 1024, kV = 32000, kK = 4;
constexpr int AR = kBT * kK;                    // 4096 rows of (bt,k)
constexpr int ROWS_H = kK * kDM;                // 4096
constexpr int ROWS_U = kK * kD2;                // 512
constexpr int ROWS_ALL = ROWS_H + ROWS_U + kK;  // 4612
constexpr int HALF_ROWS = ROWS_ALL / 2;         // 2306
constexpr int NBY = kV / 256;                   // 125 v-panels

// ---------------------------------------------------------------------------
// prep_gemm: hc/tU/ug from gc (fp32 accumulate, fp16 store).
// ---------------------------------------------------------------------------
__global__ __launch_bounds__(256) void prep_gemm(
    const float* __restrict__ gc, const float* __restrict__ Hm,
    const float* __restrict__ Um, const float* __restrict__ um,
    f16* __restrict__ hc, f16* __restrict__ tu, float* __restrict__ ug)
{
    __shared__ float sgc[8][kD1];
    const int btBase = blockIdx.x * 8;
    for (int idx = threadIdx.x; idx < 8 * kD1; idx += 256)
        sgc[idx / kD1][idx % kD1] = gc[(size_t)btBase * kD1 + idx];
    __syncthreads();

    const int rStart = blockIdx.y * HALF_ROWS;
    const int rEnd   = rStart + HALF_ROWS;
    for (int r = rStart + (int)threadIdx.x; r < rEnd; r += 256) {
        const float* wrow;
        if (r < ROWS_H)               wrow = Hm + (size_t)r * kD1;
        else if (r < ROWS_H + ROWS_U) wrow = Um + (size_t)(r - ROWS_H) * kD1;
        else                          wrow = um + (size_t)(r - ROWS_H - ROWS_U) * kD1;

        float acc[8] = {0.f,0.f,0.f,0.f,0.f,0.f,0.f,0.f};
        for (int i = 0; i < kD1; i += 4) {
            const float4 w = *reinterpret_cast<const float4*>(wrow + i);
            #pragma unroll
            for (int b = 0; b < 8; ++b) {
                const float4 g = *reinterpret_cast<const float4*>(&sgc[b][i]);
                acc[b] = fmaf(w.x, g.x, acc[b]);
                acc[b] = fmaf(w.y, g.y, acc[b]);
                acc[b] = fmaf(w.z, g.z, acc[b]);
                acc[b] = fmaf(w.w, g.w, acc[b]);
            }
        }
        #pragma unroll
        for (int b = 0; b < 8; ++b) {
            const int bt = btBase + b;
            if (r < ROWS_H) {
                const int k = r >> 10, d = r & 1023;
                hc[((size_t)(bt * kK + k) << 10) + d] = (f16)tanhf(acc[b]);
            } else if (r < ROWS_H + ROWS_U) {
                const int r2 = r - ROWS_H;
                const int k = r2 >> 7, j = r2 & 127;
                tu[(size_t)(bt * kK + k) * kD2 + j] = (f16)tanhf(acc[b]);
            } else {
                ug[bt * kK + (r - ROWS_H - ROWS_U)] = acc[b];
            }
        }
    }
}

// ---------------------------------------------------------------------------
// cvt_kernel: fp32 -> fp16, 8 elems/thread.
// ---------------------------------------------------------------------------
__global__ __launch_bounds__(256) void cvt_kernel(
    const float* __restrict__ src, f16* __restrict__ dst, int n8)
{
    const int i = blockIdx.x * 256 + threadIdx.x;
    if (i >= n8) return;
    const float4 x0 = *reinterpret_cast<const float4*>(src + (size_t)i * 8);
    const float4 x1 = *reinterpret_cast<const float4*>(src + (size_t)i * 8 + 4);
    union { f16 h[8]; uint4 v; } u;
    u.h[0] = (f16)x0.x; u.h[1] = (f16)x0.y; u.h[2] = (f16)x0.z; u.h[3] = (f16)x0.w;
    u.h[4] = (f16)x1.x; u.h[5] = (f16)x1.y; u.h[6] = (f16)x1.z; u.h[7] = (f16)x1.w;
    *reinterpret_cast<uint4*>(dst + (size_t)i * 8) = u.v;
}

__device__ __forceinline__ uint packf16x2(float a, float b) {
    union { f16 h[2]; uint u; } z;
    z.h[0] = (f16)a; z.h[1] = (f16)b;
    return z.u;
}

// ---------------------------------------------------------------------------
// fused_mfma: gate GEMM (K=128) + dots GEMM (K=1024), one 36-half stream.
// BM=256 x BN=256, 32-col halves; 8 waves (2M x 4N), wave-tile 128x64.
// LDS ring of 4 half-slots, A 16KB + B 16KB each = 128 KiB (1 block/CU).
// Swizzle: stored phys 16B slot p holds logical slot p^((row>>1)&3); read
// lane (fr,fq) -> phys fq^((fr>>1)&3); gload_lds LDS dest LINEAR, global
// source col pre-swizzled ((l&3)^((l>>3)&3))*8  (rule 21 both-sides).
// Per phase (literal G):
//   { STG(G+3): 4 gload_lds (offset imm ALWAYS 0 -- the round-8/9 NaN was
//     traced to nonzero offset immediates on global_load_lds; every passing
//     round baked the column into the pointer); s_waitcnt vmcnt(8);
//     s_barrier; 12 ds_read_b128; setprio(1); 32 MFMA; setprio(0); s_barrier }
// Ledger: at phase G after STG, outstanding = halves G+1..G+3 (12 loads);
// vmcnt(8) retires half G+1 (one phase of slack; phase G reads half G).
// WAR: STG(G+3) writes slot (G-1)&3, issued after bar2(G-1), by which all
// waves' reads of that slot completed. Tail vmcnt: 8 -> 4 -> 0 -> 0.
// The pi block's 12 scalar loads force a compiler vmcnt(0) there (one-time
// drain, correctness-neutral).
// Register budget: 8 waves = 2/SIMD => 256-reg cap; ugv/bb transient in the
// pi block; peak ~= acc 128 + pi 64 + ~30 working < 256 (no scratch).
// ---------------------------------------------------------------------------
__global__ __launch_bounds__(512, 2) void fused_mfma(
    const f16* __restrict__ hc,  const f16* __restrict__ tu,
    const f16* __restrict__ v16, const f16* __restrict__ e16,
    const float* __restrict__ ug, const float* __restrict__ bmat,
    float* __restrict__ out, float* __restrict__ psum)
{
    __shared__ __align__(16) f16 sA[4][256 * 32];   // 64 KiB
    __shared__ __align__(16) f16 sB[4][256 * 32];   // 64 KiB

    const int tid  = threadIdx.x;
    const int lane = tid & 63;
    const int wave = tid >> 6;
    const int fr = lane & 15, fq = lane >> 4;
    const int wm = wave >> 2, wc = wave & 3;         // 2 x 4 wave grid

    const int bx = blockIdx.x;            // 0..15  (fastest: B-panel sharing)
    const int by = blockIdx.y;            // 0..124
    const int aRowBase = bx * 256;
    const int vBase    = by * 256;
    const int btB      = bx * 64 + wm * 32;

    // ---- staging geometry: linear LDS dest, inverse-swizzled global col ----
    const int srowL = lane >> 2;                              // 0..15
    const int scolL = ((lane & 3) ^ ((lane >> 3) & 3)) * 8;   // f16 units
    const int loffD = srowL * kDM + scolL;
    const int loffG = srowL * kD2 + scolL;

    const f16* pA = hc  + (size_t)aRowBase * kDM + loffD;
    const f16* pB = e16 + (size_t)vBase    * kDM + loffD;
    const f16* qA = tu  + (size_t)aRowBase * kD2 + loffG;
    const f16* qB = v16 + (size_t)vBase    * kD2 + loffG;

    f16* dA0 = &sA[0][0] + (wave * 2 + 0) * 512;
    f16* dA1 = &sA[0][0] + (wave * 2 + 1) * 512;
    f16* dB0 = &sB[0][0] + (wave * 2 + 0) * 512;
    f16* dB1 = &sB[0][0] + (wave * 2 + 1) * 512;

    // ---- read-side bases (lane-constant swizzle) ----
    const int rslot = (fq ^ ((fr >> 1) & 3)) * 8;             // f16 units
    const f16* rA = &sA[0][0] + (wm * 128 + fr) * 32 + rslot;
    const f16* rB = &sB[0][0] + (wc * 64  + fr) * 32 + rslot;

#define GLD(SRC, DST)                                                         \
    __builtin_amdgcn_global_load_lds(                                         \
        (const __attribute__((address_space(1))) void*)(SRC),                 \
        (__attribute__((address_space(3))) void*)(DST), 16, 0, 0)

#define STG(G) do {                                                           \
        constexpr int SL_  = (G) & 3;                                         \
        constexpr int COL_ = ((G) < 4 ? (G) : (G) - 4) * 32;                  \
        constexpr int CS_  = ((G) < 4 ? kD2 : kDM) * 16;                      \
        const f16* A_ = ((G) < 4 ? qA : pA) + COL_;                           \
        const f16* B_ = ((G) < 4 ? qB : pB) + COL_;                           \
        GLD(A_ + (wave * 2 + 0) * CS_, dA0 + SL_ * 8192);                     \
        GLD(A_ + (wave * 2 + 1) * CS_, dA1 + SL_ * 8192);                     \
        GLD(B_ + (wave * 2 + 0) * CS_, dB0 + SL_ * 8192);                     \
        GLD(B_ + (wave * 2 + 1) * CS_, dB1 + SL_ * 8192);                     \
    } while (0)

#define PHASE(G, VM, DOSTG)                                                   \
    {                                                                         \
        DOSTG;                                                                \
        asm volatile("s_waitcnt vmcnt(" VM ")" ::: "memory");                 \
        __builtin_amdgcn_s_barrier();                                         \
        asm volatile("" ::: "memory");                                        \
        constexpr int SL_ = (G) & 3;                                          \
        f16x8 bfr_[4];                                                        \
        _Pragma("unroll")                                                     \
        for (int n = 0; n < 4; ++n)                                           \
            bfr_[n] = *reinterpret_cast<const f16x8*>(                        \
                rB + SL_ * 8192 + n * 512);                                   \
        __builtin_amdgcn_s_setprio(1);                                        \
        _Pragma("unroll")                                                     \
        for (int m = 0; m < 8; ++m) {                                         \
            const f16x8 afr_ = *reinterpret_cast<const f16x8*>(               \
                rA + SL_ * 8192 + m * 512);                                   \
            _Pragma("unroll")                                                 \
            for (int n = 0; n < 4; ++n)                                       \
                acc[m][n] = __builtin_amdgcn_mfma_f32_16x16x32_f16(           \
                    afr_, bfr_[n], acc[m][n], 0, 0, 0);                       \
        }                                                                     \
        __builtin_amdgcn_s_setprio(0);                                        \
        asm volatile("" ::: "memory");                                        \
        __builtin_amdgcn_s_barrier();                                         \
        asm volatile("" ::: "memory");                                        \
    }
#define PH(G) PHASE(G, "8", STG((G) + 3))
#define PH4(G) PH(G) PH((G) + 1) PH((G) + 2) PH((G) + 3)

    f32x4 acc[8][4];
    const f32x4 zz = {0.f, 0.f, 0.f, 0.f};
    #pragma unroll
    for (int m = 0; m < 8; ++m)
        #pragma unroll
        for (int n = 0; n < 4; ++n) acc[m][n] = zz;

    // ---------------- prologue: halves 0,1,2 in flight ----------------
    STG(0); STG(1); STG(2);

    // ---------------- gate phases 0..3 (D2 = 128) ----------------
    PH4(0)

    // ---------------- pi conversion (transient loads, registers only) ------
    uint pi01[8][4], pi23[8][4];
    {
        float4 bb[4];
        #pragma unroll
        for (int n = 0; n < 4; ++n)
            bb[n] = *reinterpret_cast<const float4*>(
                bmat + (size_t)(vBase + wc * 64 + n * 16 + fr) * 4);
        #pragma unroll
        for (int m = 0; m < 8; ++m) {
            const float4 ugv = *reinterpret_cast<const float4*>(
                ug + (btB + m * 4 + fq) * 4);
            #pragma unroll
            for (int n = 0; n < 4; ++n) {
                const float l0 = acc[m][n][0] + ugv.x + bb[n].x;
                const float l1 = acc[m][n][1] + ugv.y + bb[n].y;
                const float l2 = acc[m][n][2] + ugv.z + bb[n].z;
                const float g0 = 1.f / (1.f + __expf(-l0));
                const float g1 = 1.f / (1.f + __expf(-l1));
                const float g2 = 1.f / (1.f + __expf(-l2));
                pi01[m][n] = packf16x2(g0 * g1, g0 * (1.f - g1));
                pi23[m][n] = packf16x2((1.f - g0) * g2, (1.f - g0) * (1.f - g2));
            }
        }
    }
    #pragma unroll
    for (int m = 0; m < 8; ++m)
        #pragma unroll
        for (int n = 0; n < 4; ++n) acc[m][n] = zz;

    // ---------------- dots phases 4..35 (DM = 1024) ----------------
    PH4(4) PH4(8) PH4(12) PH4(16) PH4(20) PH4(24) PH4(28)
    PH(32)
    PHASE(33, "4", (void)0)
    PHASE(34, "0", (void)0)
    PHASE(35, "0", (void)0)
#undef PH4
#undef PH
#undef PHASE
#undef STG
#undef GLD

    // ---------------- epilogue: logits + exp partial sums ----------------
    #pragma unroll
    for (int m = 0; m < 8; ++m) {
        const int bt = btB + m * 4 + fq;
        float es = 0.f;
        #pragma unroll
        for (int n = 0; n < 4; ++n) {
            const int v = vBase + wc * 64 + n * 16 + fr;
            union { uint u; f16 h[2]; } p01, p23;
            p01.u = pi01[m][n]; p23.u = pi23[m][n];
            const float lg = (float)p01.h[0] * acc[m][n][0]
                           + (float)p01.h[1] * acc[m][n][1]
                           + (float)p23.h[0] * acc[m][n][2]
                           + (float)p23.h[1] * acc[m][n][3];
            out[(size_t)bt * kV + v] = lg;
            es += __expf(lg);
        }
        es += __shfl_xor(es, 1);
        es += __shfl_xor(es, 2);
        es += __shfl_xor(es, 4);
        es += __shfl_xor(es, 8);
        if (fr == 0)
            psum[(size_t)bt * 512 + by * 4 + wc] = es;
    }
}

// ---------------------------------------------------------------------------
// softmax scale pass: denominator from psum partials.
// ---------------------------------------------------------------------------
__global__ __launch_bounds__(256) void softmax_kernel(
    float* __restrict__ out, const float* __restrict__ psum)
{
    __shared__ float red[4];
    const int bt = blockIdx.x;
    float* row = out + (size_t)bt * kV;
    const int tid = threadIdx.x;

    float s = 0.f;
    for (int i = tid; i < 4 * NBY; i += 256) s += psum[(size_t)bt * 512 + i];
    #pragma unroll
    for (int o = 1; o < 64; o <<= 1) s += __shfl_xor(s, o);
    if ((tid & 63) == 0) red[tid >> 6] = s;
    __syncthreads();
    s = red[0] + red[1] + red[2] + red[3];
    const float inv = 1.f / s;

    for (int i = tid * 4; i < kV; i += 1024) {
        const float4 x = *reinterpret_cast<const float4*>(row + i);
        float4 y;
        y.x = __expf(x.x) * inv;
        y.y = __expf(x.y) * inv;
        y.z = __expf(x.z) * inv;
        y.w = __expf(x.w) * inv;
        *reinterpret_cast<float4*>(row + i) = y;
    }
}

} // namespace

extern "C" void kernel_launch(void* const* d_in, const int* in_sizes, int n_in,
                              void* d_out, int out_size, void* d_ws, size_t ws_size,
                              hipStream_t stream)
{
    (void)in_sizes; (void)n_in; (void)out_size; (void)ws_size;
    const float* gc   = (const float*)d_in[0];
    const float* Hm   = (const float*)d_in[1];
    const float* Um   = (const float*)d_in[2];
    const float* vmat = (const float*)d_in[3];
    const float* um   = (const float*)d_in[4];
    const float* bmat = (const float*)d_in[5];
    const float* emb  = (const float*)d_in[6];
    float* out = (float*)d_out;

    size_t off = 0;
    auto take = [&](size_t bytes) -> char* {
        char* p = (char*)d_ws + off;
        off += (bytes + 255) & ~(size_t)255;
        return p;
    };
    f16*   hc   = (f16*)  take((size_t)AR * kDM * 2);   // 8 MB
    f16*   tu   = (f16*)  take((size_t)AR * kD2 * 2);   // 1 MB
    f16*   v16  = (f16*)  take((size_t)kV * kD2 * 2);   // 8 MB
    f16*   e16  = (f16*)  take((size_t)kV * kDM * 2);   // 64 MB
    float* ug   = (float*)take((size_t)AR * 4);
    float* psum = (float*)take((size_t)kBT * 512 * 4);  // 2 MB

    prep_gemm<<<dim3(kBT / 8, 2), 256, 0, stream>>>(gc, Hm, Um, um, hc, tu, ug);
    cvt_kernel<<<(kV * kD2 / 8 + 255) / 256, 256, 0, stream>>>(vmat, v16, kV * kD2 / 8);
    cvt_kernel<<<(kV * kDM / 8 + 255) / 256, 256, 0, stream>>>(emb, e16, kV * kDM / 8);
    fused_mfma<<<dim3(AR / 256, NBY), 512, 0, stream>>>(
        hc, tu, v16, e16, ug, bmat, out, psum);
    softmax_kernel<<<dim3(kBT), 256, 0, stream>>>(out, psum);
}

// Round 13
// 561.444 us; speedup vs baseline: 1.2016x; 1.2016x over previous
//
#include <hip/hip_runtime.h>
#include <math.h>

namespace {

typedef _Float16 f16;
typedef _Float16 f16x8 __attribute__((ext_vector_type(8)));
typedef float    f32x4 __attribute__((ext_vector_type(4)));

constexpr int kBT = 1024, kD1 = 256, kD2 = 128, kDM = 1024, kV = 32000, kK = 4;
constexpr int AR = kBT * kK;                    // 4096 rows of (bt,k)
constexpr int ROWS_H = kK * kDM;                // 4096
constexpr int ROWS_U = kK * kD2;                // 512
constexpr int ROWS_ALL = ROWS_H + ROWS_U + kK;  // 4612
constexpr int HALF_ROWS = ROWS_ALL / 2;         // 2306
constexpr int NBY = kV / 128;                   // 250 v-panels

// ---------------------------------------------------------------------------
// prep_gemm: hc/tU/ug from gc (fp32 accumulate, fp16 store).
// ---------------------------------------------------------------------------
__global__ __launch_bounds__(256) void prep_gemm(
    const float* __restrict__ gc, const float* __restrict__ Hm,
    const float* __restrict__ Um, const float* __restrict__ um,
    f16* __restrict__ hc, f16* __restrict__ tu, float* __restrict__ ug)
{
    __shared__ float sgc[8][kD1];
    const int btBase = blockIdx.x * 8;
    for (int idx = threadIdx.x; idx < 8 * kD1; idx += 256)
        sgc[idx / kD1][idx % kD1] = gc[(size_t)btBase * kD1 + idx];
    __syncthreads();

    const int rStart = blockIdx.y * HALF_ROWS;
    const int rEnd   = rStart + HALF_ROWS;
    for (int r = rStart + (int)threadIdx.x; r < rEnd; r += 256) {
        const float* wrow;
        if (r < ROWS_H)               wrow = Hm + (size_t)r * kD1;
        else if (r < ROWS_H + ROWS_U) wrow = Um + (size_t)(r - ROWS_H) * kD1;
        else                          wrow = um + (size_t)(r - ROWS_H - ROWS_U) * kD1;

        float acc[8] = {0.f,0.f,0.f,0.f,0.f,0.f,0.f,0.f};
        for (int i = 0; i < kD1; i += 4) {
            const float4 w = *reinterpret_cast<const float4*>(wrow + i);
            #pragma unroll
            for (int b = 0; b < 8; ++b) {
                const float4 g = *reinterpret_cast<const float4*>(&sgc[b][i]);
                acc[b] = fmaf(w.x, g.x, acc[b]);
                acc[b] = fmaf(w.y, g.y, acc[b]);
                acc[b] = fmaf(w.z, g.z, acc[b]);
                acc[b] = fmaf(w.w, g.w, acc[b]);
            }
        }
        #pragma unroll
        for (int b = 0; b < 8; ++b) {
            const int bt = btBase + b;
            if (r < ROWS_H) {
                const int k = r >> 10, d = r & 1023;
                hc[((size_t)(bt * kK + k) << 10) + d] = (f16)tanhf(acc[b]);
            } else if (r < ROWS_H + ROWS_U) {
                const int r2 = r - ROWS_H;
                const int k = r2 >> 7, j = r2 & 127;
                tu[(size_t)(bt * kK + k) * kD2 + j] = (f16)tanhf(acc[b]);
            } else {
                ug[bt * kK + (r - ROWS_H - ROWS_U)] = acc[b];
            }
        }
    }
}

// ---------------------------------------------------------------------------
// cvt_kernel: fp32 -> fp16, 8 elems/thread.
// ---------------------------------------------------------------------------
__global__ __launch_bounds__(256) void cvt_kernel(
    const float* __restrict__ src, f16* __restrict__ dst, int n8)
{
    const int i = blockIdx.x * 256 + threadIdx.x;
    if (i >= n8) return;
    const float4 x0 = *reinterpret_cast<const float4*>(src + (size_t)i * 8);
    const float4 x1 = *reinterpret_cast<const float4*>(src + (size_t)i * 8 + 4);
    union { f16 h[8]; uint4 v; } u;
    u.h[0] = (f16)x0.x; u.h[1] = (f16)x0.y; u.h[2] = (f16)x0.z; u.h[3] = (f16)x0.w;
    u.h[4] = (f16)x1.x; u.h[5] = (f16)x1.y; u.h[6] = (f16)x1.z; u.h[7] = (f16)x1.w;
    *reinterpret_cast<uint4*>(dst + (size_t)i * 8) = u.v;
}

__device__ __forceinline__ uint packf16x2(float a, float b) {
    union { f16 h[2]; uint u; } z;
    z.h[0] = (f16)a; z.h[1] = (f16)b;
    return z.u;
}

// ---------------------------------------------------------------------------
// fused_mfma: gate GEMM (K=128, 2 tiles) + dots GEMM (K=1024, 16 tiles).
// EXACT round-5 structure (proven 385us, 104 VGPR, 0 conflicts, 2 blk/CU):
// 128x128 tile, BK=64, 4 waves (2x2), dbuf LDS 64 KiB, runtime-t loops,
// XOR-swizzled global_load_lds staging (offset imm 0, col in pointer),
// counted s_waitcnt vmcnt(8) + raw s_barrier.
// Changes vs round 5 (each individually proven elsewhere):
//  (a) lane-constant LDS read bases (ps=(kk*4+fq)^(r&7), r&7==fr&7) --
//      pure strength reduction, bit-identical addresses, same 8-temp shape;
//  (b) setprio(1)/(0) around each 16-MFMA cluster (rounds 6/7/11);
//  (c) epilogue emits per-(bt,block) sum of exp -> psum (round 7).
// ---------------------------------------------------------------------------
__global__ __launch_bounds__(256, 2) void fused_mfma(
    const f16* __restrict__ hc,  const f16* __restrict__ tu,
    const f16* __restrict__ v16, const f16* __restrict__ e16,
    const float* __restrict__ ug, const float* __restrict__ bmat,
    float* __restrict__ out, float* __restrict__ psum)
{
    __shared__ __align__(16) f16 sA[2][128 * 64];   // 32 KiB
    __shared__ __align__(16) f16 sB[2][128 * 64];   // 32 KiB

    constexpr int NT_G = kD2 / 64;       // 2 gate tiles
    constexpr int NT   = NT_G + kDM / 64; // 18 tiles total

    const int tid  = threadIdx.x;
    const int lane = tid & 63;
    const int wave = tid >> 6;
    const int fr = lane & 15, fq = lane >> 4;
    const int wrow = wave >> 1, wcol = wave & 1;
    const int aRowBase = blockIdx.x * 128;
    const int vBase    = blockIdx.y * 128;
    const int btB      = blockIdx.x * 32 + wrow * 16;

    // staging geometry: chunk = 8 rows x 128B; lane l -> row srow, phys slot
    // l&7, which must hold logical slot (l&7)^(srow&7)  (inverse swizzle).
    const int srow = lane >> 3;
    const int scol = ((lane & 7) ^ srow) * 8;   // logical column (f16 units)

    // stage tile t (8 global_load_lds per thread) into buffer t&1.
    auto stage_tile = [&](int t) {
        const bool g = (t < NT_G);
        const f16* A = g ? tu  : hc;
        const f16* B = g ? v16 : e16;
        const int stride = g ? kD2 : kDM;
        const int dB = g ? t * 64 : (t - NT_G) * 64;
        f16* da = &sA[t & 1][0];
        f16* db = &sB[t & 1][0];
        #pragma unroll
        for (int i = 0; i < 4; ++i) {
            const int c = wave * 4 + i;                 // chunk 0..15
            const f16* srcA = A + (size_t)(aRowBase + c * 8 + srow) * stride + dB + scol;
            __builtin_amdgcn_global_load_lds(
                (const __attribute__((address_space(1))) void*)srcA,
                (__attribute__((address_space(3))) void*)(da + c * 512), 16, 0, 0);
            const f16* srcB = B + (size_t)(vBase + c * 8 + srow) * stride + dB + scol;
            __builtin_amdgcn_global_load_lds(
                (const __attribute__((address_space(1))) void*)srcB,
                (__attribute__((address_space(3))) void*)(db + c * 512), 16, 0, 0);
        }
    };

    // lane-constant read bases: ps(kk) = (kk*4+fq)^(fr&7)  (r&7 == fr&7
    // since r = wrow*64 + m*16 + fr and 64|wrow*64, 8|m*16).
    const int ps0 = (fq ^ (fr & 7)) * 8;
    const int ps1 = ((4 + fq) ^ (fr & 7)) * 8;
    const f16* rA0 = &sA[0][0] + (wrow * 64 + fr) * 64 + ps0;
    const f16* rA1 = &sA[0][0] + (wrow * 64 + fr) * 64 + ps1;
    const f16* rB0 = &sB[0][0] + (wcol * 64 + fr) * 64 + ps0;
    const f16* rB1 = &sB[0][0] + (wcol * 64 + fr) * 64 + ps1;

    auto mmStep = [&](f32x4 (&acc)[4][4], int q) {
        const int qo = q * 8192;
        {
            f16x8 a[4], b[4];
            #pragma unroll
            for (int m = 0; m < 4; ++m)
                a[m] = *reinterpret_cast<const f16x8*>(rA0 + qo + m * 1024);
            #pragma unroll
            for (int n = 0; n < 4; ++n)
                b[n] = *reinterpret_cast<const f16x8*>(rB0 + qo + n * 1024);
            __builtin_amdgcn_s_setprio(1);
            #pragma unroll
            for (int m = 0; m < 4; ++m)
                #pragma unroll
                for (int n = 0; n < 4; ++n)
                    acc[m][n] = __builtin_amdgcn_mfma_f32_16x16x32_f16(
                        a[m], b[n], acc[m][n], 0, 0, 0);
            __builtin_amdgcn_s_setprio(0);
        }
        {
            f16x8 a[4], b[4];
            #pragma unroll
            for (int m = 0; m < 4; ++m)
                a[m] = *reinterpret_cast<const f16x8*>(rA1 + qo + m * 1024);
            #pragma unroll
            for (int n = 0; n < 4; ++n)
                b[n] = *reinterpret_cast<const f16x8*>(rB1 + qo + n * 1024);
            __builtin_amdgcn_s_setprio(1);
            #pragma unroll
            for (int m = 0; m < 4; ++m)
                #pragma unroll
                for (int n = 0; n < 4; ++n)
                    acc[m][n] = __builtin_amdgcn_mfma_f32_16x16x32_f16(
                        a[m], b[n], acc[m][n], 0, 0, 0);
            __builtin_amdgcn_s_setprio(0);
        }
    };

    const f32x4 zz = {0.f, 0.f, 0.f, 0.f};

    // ---------------- gate phase: 2 tiles over D2 ----------------
    f32x4 gacc[4][4];
    #pragma unroll
    for (int m = 0; m < 4; ++m)
        #pragma unroll
        for (int n = 0; n < 4; ++n) gacc[m][n] = zz;

    stage_tile(0);
    for (int t = 0; t < NT_G; ++t) {
        stage_tile(t + 1);                     // t=1 stages dots tile 0
        asm volatile("s_waitcnt vmcnt(8)" ::: "memory");
        __builtin_amdgcn_s_barrier();          // tile t resident in LDS
        mmStep(gacc, t & 1);
        asm volatile("" ::: "memory");
        __builtin_amdgcn_s_barrier();          // buf t&1 free for reuse
    }

    // ---------------- pi conversion (registers only) ----------------
    uint pi01[4][4], pi23[4][4];
    {
        float4 bb[4];
        #pragma unroll
        for (int n = 0; n < 4; ++n)
            bb[n] = *reinterpret_cast<const float4*>(
                bmat + (size_t)(vBase + wcol * 64 + n * 16 + fr) * 4);
        #pragma unroll
        for (int m = 0; m < 4; ++m) {
            const float4 ugv = *reinterpret_cast<const float4*>(
                ug + (btB + m * 4 + fq) * 4);
            #pragma unroll
            for (int n = 0; n < 4; ++n) {
                const float l0 = gacc[m][n][0] + ugv.x + bb[n].x;
                const float l1 = gacc[m][n][1] + ugv.y + bb[n].y;
                const float l2 = gacc[m][n][2] + ugv.z + bb[n].z;
                const float g0 = 1.f / (1.f + __expf(-l0));
                const float g1 = 1.f / (1.f + __expf(-l1));
                const float g2 = 1.f / (1.f + __expf(-l2));
                pi01[m][n] = packf16x2(g0 * g1, g0 * (1.f - g1));
                pi23[m][n] = packf16x2((1.f - g0) * g2, (1.f - g0) * (1.f - g2));
            }
        }
    }

    // ---------------- dots phase: 16 tiles over DM ----------------
    f32x4 dacc[4][4];
    #pragma unroll
    for (int m = 0; m < 4; ++m)
        #pragma unroll
        for (int n = 0; n < 4; ++n) dacc[m][n] = zz;

    for (int t = NT_G; t < NT - 1; ++t) {
        stage_tile(t + 1);
        asm volatile("s_waitcnt vmcnt(8)" ::: "memory");
        __builtin_amdgcn_s_barrier();
        mmStep(dacc, t & 1);
        asm volatile("" ::: "memory");
        __builtin_amdgcn_s_barrier();
    }
    // last tile: drain and compute (no prefetch).
    asm volatile("s_waitcnt vmcnt(0)" ::: "memory");
    __builtin_amdgcn_s_barrier();
    mmStep(dacc, (NT - 1) & 1);

    // ---------------- epilogue: logits + exp partial sums ----------------
    #pragma unroll
    for (int m = 0; m < 4; ++m) {
        const int bt = btB + m * 4 + fq;
        float es = 0.f;
        #pragma unroll
        for (int n = 0; n < 4; ++n) {
            const int v = vBase + wcol * 64 + n * 16 + fr;
            union { uint u; f16 h[2]; } p01, p23;
            p01.u = pi01[m][n]; p23.u = pi23[m][n];
            const float lg = (float)p01.h[0] * dacc[m][n][0]
                           + (float)p01.h[1] * dacc[m][n][1]
                           + (float)p23.h[0] * dacc[m][n][2]
                           + (float)p23.h[1] * dacc[m][n][3];
            out[(size_t)bt * kV + v] = lg;
            es += __expf(lg);
        }
        // reduce over the 16-lane fr group (same bt).
        es += __shfl_xor(es, 1);
        es += __shfl_xor(es, 2);
        es += __shfl_xor(es, 4);
        es += __shfl_xor(es, 8);
        if (fr == 0)
            psum[(size_t)bt * 512 + blockIdx.y * 2 + wcol] = es;
    }
}

// ---------------------------------------------------------------------------
// softmax scale pass: denominator from psum partials (sum pass fused away).
// ---------------------------------------------------------------------------
__global__ __launch_bounds__(256) void softmax_kernel(
    float* __restrict__ out, const float* __restrict__ psum)
{
    __shared__ float red[4];
    const int bt = blockIdx.x;
    float* row = out + (size_t)bt * kV;
    const int tid = threadIdx.x;

    float s = 0.f;
    for (int i = tid; i < 2 * NBY; i += 256) s += psum[(size_t)bt * 512 + i];
    #pragma unroll
    for (int o = 1; o < 64; o <<= 1) s += __shfl_xor(s, o);
    if ((tid & 63) == 0) red[tid >> 6] = s;
    __syncthreads();
    s = red[0] + red[1] + red[2] + red[3];
    const float inv = 1.f / s;

    for (int i = tid * 4; i < kV; i += 1024) {
        const float4 x = *reinterpret_cast<const float4*>(row + i);
        float4 y;
        y.x = __expf(x.x) * inv;
        y.y = __expf(x.y) * inv;
        y.z = __expf(x.z) * inv;
        y.w = __expf(x.w) * inv;
        *reinterpret_cast<float4*>(row + i) = y;
    }
}

} // namespace

extern "C" void kernel_launch(void* const* d_in, const int* in_sizes, int n_in,
                              void* d_out, int out_size, void* d_ws, size_t ws_size,
                              hipStream_t stream)
{
    (void)in_sizes; (void)n_in; (void)out_size; (void)ws_size;
    const float* gc   = (const float*)d_in[0];
    const float* Hm   = (const float*)d_in[1];
    const float* Um   = (const float*)d_in[2];
    const float* vmat = (const float*)d_in[3];
    const float* um   = (const float*)d_in[4];
    const float* bmat = (const float*)d_in[5];
    const float* emb  = (const float*)d_in[6];
    float* out = (float*)d_out;

    size_t off = 0;
    auto take = [&](size_t bytes) -> char* {
        char* p = (char*)d_ws + off;
        off += (bytes + 255) & ~(size_t)255;
        return p;
    };
    f16*   hc   = (f16*)  take((size_t)AR * kDM * 2);   // 8 MB
    f16*   tu   = (f16*)  take((size_t)AR * kD2 * 2);   // 1 MB
    f16*   v16  = (f16*)  take((size_t)kV * kD2 * 2);   // 8 MB
    f16*   e16  = (f16*)  take((size_t)kV * kDM * 2);   // 64 MB
    float* ug   = (float*)take((size_t)AR * 4);
    float* psum = (float*)take((size_t)kBT * 512 * 4);  // 2 MB

    prep_gemm<<<dim3(kBT / 8, 2), 256, 0, stream>>>(gc, Hm, Um, um, hc, tu, ug);
    cvt_kernel<<<(kV * kD2 / 8 + 255) / 256, 256, 0, stream>>>(vmat, v16, kV * kD2 / 8);
    cvt_kernel<<<(kV * kDM / 8 + 255) / 256, 256, 0, stream>>>(emb, e16, kV * kDM / 8);
    fused_mfma<<<dim3(AR / 128, NBY), 256, 0, stream>>>(
        hc, tu, v16, e16, ug, bmat, out, psum);
    softmax_kernel<<<dim3(kBT), 256, 0, stream>>>(out, psum);
}

// Round 14
// 531.181 us; speedup vs baseline: 1.2701x; 1.0570x over previous
//
#include <hip/hip_runtime.h>
#include <math.h>

namespace {

typedef _Float16 f16;
typedef _Float16 f16x8 __attribute__((ext_vector_type(8)));
typedef float    f32x4 __attribute__((ext_vector_type(4)));

constexpr int kBT = 1024, kD1 = 256, kD2 = 128, kDM = 1024, kV = 32000, kK = 4;
constexpr int AR = kBT * kK;                    // 4096 rows of (bt,k)
constexpr int ROWS_H = kK * kDM;                // 4096
constexpr int ROWS_U = kK * kD2;                // 512
constexpr int ROWS_ALL = ROWS_H + ROWS_U + kK;  // 4612
constexpr int SLICES = 8;
constexpr int SLICE_ROWS = (ROWS_ALL + SLICES - 1) / SLICES;  // 577
constexpr int NBY = kV / 128;                   // 250 v-panels

// ---------------------------------------------------------------------------
// prep_gemm: hc/tU/ug from gc (fp32 accumulate, fp16 store).
// Grid (128, 8): 1024 blocks -> 4 blocks/CU (was 256 = 1/CU, latency-bound).
// ---------------------------------------------------------------------------
__global__ __launch_bounds__(256) void prep_gemm(
    const float* __restrict__ gc, const float* __restrict__ Hm,
    const float* __restrict__ Um, const float* __restrict__ um,
    f16* __restrict__ hc, f16* __restrict__ tu, float* __restrict__ ug)
{
    __shared__ float sgc[8][kD1];
    const int btBase = blockIdx.x * 8;
    for (int idx = threadIdx.x; idx < 8 * kD1; idx += 256)
        sgc[idx / kD1][idx % kD1] = gc[(size_t)btBase * kD1 + idx];
    __syncthreads();

    const int rStart = blockIdx.y * SLICE_ROWS;
    int rEnd = rStart + SLICE_ROWS;
    if (rEnd > ROWS_ALL) rEnd = ROWS_ALL;
    for (int r = rStart + (int)threadIdx.x; r < rEnd; r += 256) {
        const float* wrow;
        if (r < ROWS_H)               wrow = Hm + (size_t)r * kD1;
        else if (r < ROWS_H + ROWS_U) wrow = Um + (size_t)(r - ROWS_H) * kD1;
        else                          wrow = um + (size_t)(r - ROWS_H - ROWS_U) * kD1;

        float acc[8] = {0.f,0.f,0.f,0.f,0.f,0.f,0.f,0.f};
        for (int i = 0; i < kD1; i += 4) {
            const float4 w = *reinterpret_cast<const float4*>(wrow + i);
            #pragma unroll
            for (int b = 0; b < 8; ++b) {
                const float4 g = *reinterpret_cast<const float4*>(&sgc[b][i]);
                acc[b] = fmaf(w.x, g.x, acc[b]);
                acc[b] = fmaf(w.y, g.y, acc[b]);
                acc[b] = fmaf(w.z, g.z, acc[b]);
                acc[b] = fmaf(w.w, g.w, acc[b]);
            }
        }
        #pragma unroll
        for (int b = 0; b < 8; ++b) {
            const int bt = btBase + b;
            if (r < ROWS_H) {
                const int k = r >> 10, d = r & 1023;
                hc[((size_t)(bt * kK + k) << 10) + d] = (f16)tanhf(acc[b]);
            } else if (r < ROWS_H + ROWS_U) {
                const int r2 = r - ROWS_H;
                const int k = r2 >> 7, j = r2 & 127;
                tu[(size_t)(bt * kK + k) * kD2 + j] = (f16)tanhf(acc[b]);
            } else {
                ug[bt * kK + (r - ROWS_H - ROWS_U)] = acc[b];
            }
        }
    }
}

// ---------------------------------------------------------------------------
// cvt_kernel: fp32 -> fp16, 8 elems/thread.
// ---------------------------------------------------------------------------
__global__ __launch_bounds__(256) void cvt_kernel(
    const float* __restrict__ src, f16* __restrict__ dst, int n8)
{
    const int i = blockIdx.x * 256 + threadIdx.x;
    if (i >= n8) return;
    const float4 x0 = *reinterpret_cast<const float4*>(src + (size_t)i * 8);
    const float4 x1 = *reinterpret_cast<const float4*>(src + (size_t)i * 8 + 4);
    union { f16 h[8]; uint4 v; } u;
    u.h[0] = (f16)x0.x; u.h[1] = (f16)x0.y; u.h[2] = (f16)x0.z; u.h[3] = (f16)x0.w;
    u.h[4] = (f16)x1.x; u.h[5] = (f16)x1.y; u.h[6] = (f16)x1.z; u.h[7] = (f16)x1.w;
    *reinterpret_cast<uint4*>(dst + (size_t)i * 8) = u.v;
}

__device__ __forceinline__ uint packf16x2(float a, float b) {
    union { f16 h[2]; uint u; } z;
    z.h[0] = (f16)a; z.h[1] = (f16)b;
    return z.u;
}

// ---------------------------------------------------------------------------
// fused_mfma: gate GEMM (K=128, 2 tiles) + dots GEMM (K=1024, 16 tiles).
// Round-13 structure (proven: 401us, 108 VGPR, 0 conflicts, 2 blk/CU):
// 128x128 tile, BK=64, 4 waves (2x2), dbuf LDS 64 KiB, XOR-swizzled
// global_load_lds staging (offset imm 0), vmcnt(8) + raw s_barrier,
// lane-constant read bases, setprio around MFMA clusters, psum epilogue.
// NEW: dots staging uses RUNNING pointers (+64/tile) + pair-unrolled dots
// loop (constexpr buffer select) -> staging address VALU cut ~2x.
// Ledger unchanged: per tile T: stage(T+1) [8 loads]; vmcnt(8) [retires
// T's 8]; bar; 16 ds_read + 32 MFMA; bar. WAR: stage(T+1) writes buf
// (T+1)&1, last read at T-1, completed before bar2(T-1). Tail vmcnt(0).
// ---------------------------------------------------------------------------
__global__ __launch_bounds__(256, 2) void fused_mfma(
    const f16* __restrict__ hc,  const f16* __restrict__ tu,
    const f16* __restrict__ v16, const f16* __restrict__ e16,
    const float* __restrict__ ug, const float* __restrict__ bmat,
    float* __restrict__ out, float* __restrict__ psum)
{
    __shared__ __align__(16) f16 sA[2][128 * 64];   // 32 KiB
    __shared__ __align__(16) f16 sB[2][128 * 64];   // 32 KiB

    const int tid  = threadIdx.x;
    const int lane = tid & 63;
    const int wave = tid >> 6;
    const int fr = lane & 15, fq = lane >> 4;
    const int wrow = wave >> 1, wcol = wave & 1;
    const int aRowBase = blockIdx.x * 128;
    const int vBase    = blockIdx.y * 128;
    const int btB      = blockIdx.x * 32 + wrow * 16;

    // staging geometry: chunk c = wave*4+i covers rows wave*32+i*8 .. +8;
    // lane l -> row srow = l>>3, phys slot l&7 holds logical (l&7)^srow.
    const int srow = lane >> 3;
    const int scol = ((lane & 7) ^ srow) * 8;   // inverse-swizzled global col

    // per-thread staging bases; dots pointers advance +64 per staged tile.
    const f16* gApt = tu  + (size_t)(aRowBase + wave * 32 + srow) * kD2 + scol;
    const f16* gBpt = v16 + (size_t)(vBase    + wave * 32 + srow) * kD2 + scol;
    const f16* sApt = hc  + (size_t)(aRowBase + wave * 32 + srow) * kDM + scol;
    const f16* sBpt = e16 + (size_t)(vBase    + wave * 32 + srow) * kDM + scol;

    f16* dA = &sA[0][0] + wave * 4 * 512;   // + buf*8192 + i*512
    f16* dB = &sB[0][0] + wave * 4 * 512;

#define GLD(SRC, DST)                                                         \
    __builtin_amdgcn_global_load_lds(                                         \
        (const __attribute__((address_space(1))) void*)(SRC),                 \
        (__attribute__((address_space(3))) void*)(DST), 16, 0, 0)

    // gate tile t (t = 0,1 literal) -> buf t.
    auto stage_gate = [&](int t) {
        #pragma unroll
        for (int i = 0; i < 4; ++i) {
            GLD(gApt + t * 64 + i * 8 * kD2, dA + t * 8192 + i * 512);
            GLD(gBpt + t * 64 + i * 8 * kD2, dB + t * 8192 + i * 512);
        }
    };
    // dots tile (running pointers) -> buf.
    auto stage_dots = [&](int buf) {
        #pragma unroll
        for (int i = 0; i < 4; ++i) {
            GLD(sApt + i * 8 * kDM, dA + buf * 8192 + i * 512);
            GLD(sBpt + i * 8 * kDM, dB + buf * 8192 + i * 512);
        }
        sApt += 64; sBpt += 64;
    };

    // lane-constant read bases: ps(kk) = (kk*4+fq)^(fr&7).
    const int ps0 = (fq ^ (fr & 7)) * 8;
    const int ps1 = ((4 + fq) ^ (fr & 7)) * 8;
    const f16* rA0 = &sA[0][0] + (wrow * 64 + fr) * 64 + ps0;
    const f16* rA1 = &sA[0][0] + (wrow * 64 + fr) * 64 + ps1;
    const f16* rB0 = &sB[0][0] + (wcol * 64 + fr) * 64 + ps0;
    const f16* rB1 = &sB[0][0] + (wcol * 64 + fr) * 64 + ps1;

    auto mmStep = [&](f32x4 (&acc)[4][4], int q) {
        const int qo = q * 8192;
        {
            f16x8 a[4], b[4];
            #pragma unroll
            for (int m = 0; m < 4; ++m)
                a[m] = *reinterpret_cast<const f16x8*>(rA0 + qo + m * 1024);
            #pragma unroll
            for (int n = 0; n < 4; ++n)
                b[n] = *reinterpret_cast<const f16x8*>(rB0 + qo + n * 1024);
            __builtin_amdgcn_s_setprio(1);
            #pragma unroll
            for (int m = 0; m < 4; ++m)
                #pragma unroll
                for (int n = 0; n < 4; ++n)
                    acc[m][n] = __builtin_amdgcn_mfma_f32_16x16x32_f16(
                        a[m], b[n], acc[m][n], 0, 0, 0);
            __builtin_amdgcn_s_setprio(0);
        }
        {
            f16x8 a[4], b[4];
            #pragma unroll
            for (int m = 0; m < 4; ++m)
                a[m] = *reinterpret_cast<const f16x8*>(rA1 + qo + m * 1024);
            #pragma unroll
            for (int n = 0; n < 4; ++n)
                b[n] = *reinterpret_cast<const f16x8*>(rB1 + qo + n * 1024);
            __builtin_amdgcn_s_setprio(1);
            #pragma unroll
            for (int m = 0; m < 4; ++m)
                #pragma unroll
                for (int n = 0; n < 4; ++n)
                    acc[m][n] = __builtin_amdgcn_mfma_f32_16x16x32_f16(
                        a[m], b[n], acc[m][n], 0, 0, 0);
            __builtin_amdgcn_s_setprio(0);
        }
    };

#define WAITBAR(VM)                                                           \
    asm volatile("s_waitcnt vmcnt(" VM ")" ::: "memory");                     \
    __builtin_amdgcn_s_barrier();                                             \
    asm volatile("" ::: "memory");
#define ENDBAR                                                                \
    asm volatile("" ::: "memory");                                            \
    __builtin_amdgcn_s_barrier();                                             \
    asm volatile("" ::: "memory");

    const f32x4 zz = {0.f, 0.f, 0.f, 0.f};

    // ---------------- gate phase: tiles 0,1 over D2 ----------------
    f32x4 gacc[4][4];
    #pragma unroll
    for (int m = 0; m < 4; ++m)
        #pragma unroll
        for (int n = 0; n < 4; ++n) gacc[m][n] = zz;

    stage_gate(0);
    stage_gate(1);          WAITBAR("8")  mmStep(gacc, 0);  ENDBAR
    stage_dots(0);          WAITBAR("8")  mmStep(gacc, 1);  ENDBAR

    // ---------------- pi conversion (registers only) ----------------
    uint pi01[4][4], pi23[4][4];
    {
        float4 bb[4];
        #pragma unroll
        for (int n = 0; n < 4; ++n)
            bb[n] = *reinterpret_cast<const float4*>(
                bmat + (size_t)(vBase + wcol * 64 + n * 16 + fr) * 4);
        #pragma unroll
        for (int m = 0; m < 4; ++m) {
            const float4 ugv = *reinterpret_cast<const float4*>(
                ug + (btB + m * 4 + fq) * 4);
            #pragma unroll
            for (int n = 0; n < 4; ++n) {
                const float l0 = gacc[m][n][0] + ugv.x + bb[n].x;
                const float l1 = gacc[m][n][1] + ugv.y + bb[n].y;
                const float l2 = gacc[m][n][2] + ugv.z + bb[n].z;
                const float g0 = 1.f / (1.f + __expf(-l0));
                const float g1 = 1.f / (1.f + __expf(-l1));
                const float g2 = 1.f / (1.f + __expf(-l2));
                pi01[m][n] = packf16x2(g0 * g1, g0 * (1.f - g1));
                pi23[m][n] = packf16x2((1.f - g0) * g2, (1.f - g0) * (1.f - g2));
            }
        }
    }

    // ---------------- dots phase: 16 tiles over DM ----------------
    // compute tiles alternate buf 0,1 starting at 0; each stages the next.
    f32x4 dacc[4][4];
    #pragma unroll
    for (int m = 0; m < 4; ++m)
        #pragma unroll
        for (int n = 0; n < 4; ++n) dacc[m][n] = zz;

    for (int it = 0; it < 7; ++it) {
        stage_dots(1);      WAITBAR("8")  mmStep(dacc, 0);  ENDBAR
        stage_dots(0);      WAITBAR("8")  mmStep(dacc, 1);  ENDBAR
    }
    stage_dots(1);          WAITBAR("8")  mmStep(dacc, 0);  ENDBAR
                            WAITBAR("0")  mmStep(dacc, 1);
#undef WAITBAR
#undef ENDBAR
#undef GLD

    // ---------------- epilogue: logits + exp partial sums ----------------
    #pragma unroll
    for (int m = 0; m < 4; ++m) {
        const int bt = btB + m * 4 + fq;
        float es = 0.f;
        #pragma unroll
        for (int n = 0; n < 4; ++n) {
            const int v = vBase + wcol * 64 + n * 16 + fr;
            union { uint u; f16 h[2]; } p01, p23;
            p01.u = pi01[m][n]; p23.u = pi23[m][n];
            const float lg = (float)p01.h[0] * dacc[m][n][0]
                           + (float)p01.h[1] * dacc[m][n][1]
                           + (float)p23.h[0] * dacc[m][n][2]
                           + (float)p23.h[1] * dacc[m][n][3];
            out[(size_t)bt * kV + v] = lg;
            es += __expf(lg);
        }
        es += __shfl_xor(es, 1);
        es += __shfl_xor(es, 2);
        es += __shfl_xor(es, 4);
        es += __shfl_xor(es, 8);
        if (fr == 0)
            psum[(size_t)bt * 512 + blockIdx.y * 2 + wcol] = es;
    }
}

// ---------------------------------------------------------------------------
// softmax scale pass: denominator from psum partials (sum pass fused away).
// ---------------------------------------------------------------------------
__global__ __launch_bounds__(256) void softmax_kernel(
    float* __restrict__ out, const float* __restrict__ psum)
{
    __shared__ float red[4];
    const int bt = blockIdx.x;
    float* row = out + (size_t)bt * kV;
    const int tid = threadIdx.x;

    float s = 0.f;
    for (int i = tid; i < 2 * NBY; i += 256) s += psum[(size_t)bt * 512 + i];
    #pragma unroll
    for (int o = 1; o < 64; o <<= 1) s += __shfl_xor(s, o);
    if ((tid & 63) == 0) red[tid >> 6] = s;
    __syncthreads();
    s = red[0] + red[1] + red[2] + red[3];
    const float inv = 1.f / s;

    for (int i = tid * 4; i < kV; i += 1024) {
        const float4 x = *reinterpret_cast<const float4*>(row + i);
        float4 y;
        y.x = __expf(x.x) * inv;
        y.y = __expf(x.y) * inv;
        y.z = __expf(x.z) * inv;
        y.w = __expf(x.w) * inv;
        *reinterpret_cast<float4*>(row + i) = y;
    }
}

} // namespace

extern "C" void kernel_launch(void* const* d_in, const int* in_sizes, int n_in,
                              void* d_out, int out_size, void* d_ws, size_t ws_size,
                              hipStream_t stream)
{
    (void)in_sizes; (void)n_in; (void)out_size; (void)ws_size;
    const float* gc   = (const float*)d_in[0];
    const float* Hm   = (const float*)d_in[1];
    const float* Um   = (const float*)d_in[2];
    const float* vmat = (const float*)d_in[3];
    const float* um   = (const float*)d_in[4];
    const float* bmat = (const float*)d_in[5];
    const float* emb  = (const float*)d_in[6];
    float* out = (float*)d_out;

    size_t off = 0;
    auto take = [&](size_t bytes) -> char* {
        char* p = (char*)d_ws + off;
        off += (bytes + 255) & ~(size_t)255;
        return p;
    };
    f16*   hc   = (f16*)  take((size_t)AR * kDM * 2);   // 8 MB
    f16*   tu   = (f16*)  take((size_t)AR * kD2 * 2);   // 1 MB
    f16*   v16  = (f16*)  take((size_t)kV * kD2 * 2);   // 8 MB
    f16*   e16  = (f16*)  take((size_t)kV * kDM * 2);   // 64 MB
    float* ug   = (float*)take((size_t)AR * 4);
    float* psum = (float*)take((size_t)kBT * 512 * 4);  // 2 MB

    prep_gemm<<<dim3(kBT / 8, SLICES), 256, 0, stream>>>(gc, Hm, Um, um, hc, tu, ug);
    cvt_kernel<<<(kV * kD2 / 8 + 255) / 256, 256, 0, stream>>>(vmat, v16, kV * kD2 / 8);
    cvt_kernel<<<(kV * kDM / 8 + 255) / 256, 256, 0, stream>>>(emb, e16, kV * kDM / 8);
    fused_mfma<<<dim3(AR / 128, NBY), 256, 0, stream>>>(
        hc, tu, v16, e16, ug, bmat, out, psum);
    softmax_kernel<<<dim3(kBT), 256, 0, stream>>>(out, psum);
}